// Round 20
// baseline (780.094 us; speedup 1.0000x reference)
//
#include <hip/hip_runtime.h>
#include <hip/hip_fp16.h>
#include <math.h>

// ---------------------------------------------------------------------------
// GAT 4-layer forward.  (R20 = R19 + cached streams + degree-sorted gather;
// 11th submit — broker timeouts, never measured.)
//   R17: XCD slicing works (FETCH 238->90 MB) but 2B loads -> 213us.
//   R18: wide dwordx4 loads -> 121us, FETCH 58MB; 24x ds_bpermute reduction
//        per node-slice was the new cost (LDS-pipe throughput ~37us/layer).
//   R19: group-per-node (no reduction) -> 97us BUT (a) FETCH rose to 100MB:
//        nontemporal 2-4B src/w touches -> no L2 allocate -> line refetch
//        storm (1.37 TB/s HBM-miss-bound); (b) VALU 53->25%: wave trip =
//        max degree over its 8 nodes (divergence).
//   R20 fixes exactly those two measured regressions:
//     - src/w loads are REGULAR (L2-cached); only outputs stay nontemporal.
//     - nodes are counting-sorted by degree (reuses counts[] + scan kernel);
//       gather waves take 8 nodes of adjacent degree rank -> trip ~= avg deg.
//   Everything else unchanged: stats_kernel (head-major w), GEMM, conv
//   prologue, CSR build, slice->XCD affinity.
// ---------------------------------------------------------------------------

typedef __attribute__((ext_vector_type(8))) _Float16 f16x8;
typedef __attribute__((ext_vector_type(4))) float floatx4;
typedef __attribute__((ext_vector_type(8))) unsigned short usv8;
typedef __attribute__((ext_vector_type(4))) unsigned short usv4;

#define DEG_CAP 256
#define DBUCKETS 1024

__device__ __forceinline__ float lrelu(float e) {
    return (e > 0.f) ? e : 0.2f * e;
}
__device__ __forceinline__ void gload16(const void* g, void* l) {
    __builtin_amdgcn_global_load_lds(
        (const __attribute__((address_space(1))) void*)g,
        (__attribute__((address_space(3))) void*)l, 16, 0, 0);
}
__device__ __forceinline__ float ushort2floath(unsigned short u) {
    union { unsigned short u; __half h; } cv;
    cv.u = u;
    return __half2float(cv.h);
}

// ---------------------------------------------------------------------------
// CSR build
// ---------------------------------------------------------------------------
static __global__ void zero_int(int* __restrict__ p, int n) {
    int i = blockIdx.x * blockDim.x + threadIdx.x;
    if (i < n) p[i] = 0;
}

static __global__ void hist_kernel(const int* __restrict__ ei, int e0, int n_nodes,
                                   int* __restrict__ counts) {
    int e = blockIdx.x * blockDim.x + threadIdx.x;
    int et = e0 + n_nodes;
    if (e >= et) return;
    int d = (e < e0) ? ei[e0 + e] : (e - e0);
    atomicAdd(&counts[d], 1);
}

static __global__ void scan_kernel(const int* __restrict__ counts,
                                   int* __restrict__ row_ptr,
                                   int* __restrict__ cursor, int n) {
    __shared__ int sdata[1024];
    int tid = threadIdx.x;
    int per = (n + 1023) / 1024;
    int start = tid * per;
    int stop = min(start + per, n);
    if (start > n) start = n;
    int s = 0;
    for (int i = start; i < stop; i++) s += counts[i];
    sdata[tid] = s;
    __syncthreads();
    for (int off = 1; off < 1024; off <<= 1) {
        int t = (tid >= off) ? sdata[tid - off] : 0;
        __syncthreads();
        sdata[tid] += t;
        __syncthreads();
    }
    int run = sdata[tid] - s;
    for (int i = start; i < stop; i++) {
        row_ptr[i] = run;
        cursor[i] = run;
        run += counts[i];
    }
    if (stop == n) row_ptr[n] = run;
}

static __global__ void scatter_kernel(const int* __restrict__ ei, int e0, int n_nodes,
                                      int* __restrict__ cursor,
                                      int* __restrict__ src_sorted) {
    int e = blockIdx.x * blockDim.x + threadIdx.x;
    int et = e0 + n_nodes;
    if (e >= et) return;
    int s, d;
    if (e < e0) { s = ei[e]; d = ei[e0 + e]; } else { s = e - e0; d = s; }
    int pos = atomicAdd(&cursor[d], 1);
    src_sorted[pos] = s;
}

// ---- degree counting sort (balances gather waves) ----
static __global__ void deg_hist_kernel(const int* __restrict__ counts, int n,
                                       int* __restrict__ dhist) {
    int i = blockIdx.x * blockDim.x + threadIdx.x;
    if (i >= n) return;
    int b = min(counts[i], DBUCKETS - 1);
    atomicAdd(&dhist[b], 1);
}

static __global__ void order_scatter_kernel(const int* __restrict__ counts, int n,
                                            int* __restrict__ dcur,
                                            int* __restrict__ node_order) {
    int i = blockIdx.x * blockDim.x + threadIdx.x;
    if (i >= n) return;
    int b = min(counts[i], DBUCKETS - 1);
    int pos = atomicAdd(&dcur[b], 1);
    node_order[pos] = i;
}

// ---------------------------------------------------------------------------
// fused conversion prologue: x -> fp16 A, 4x W -> fp16 W^T, zero as/ad.
// ---------------------------------------------------------------------------
__device__ __forceinline__ void convW_one(const float* W, __half* BT,
                                          int idx, int K, int N) {
    int n = idx / K, k = idx % K;
    float v = (n < N) ? W[(size_t)k * N + n] : 0.f;
    BT[(size_t)n * K + k] = __float2half(v);
}

static __global__ void conv_all(const float* __restrict__ X, __half* __restrict__ A, int nx,
                                const float* __restrict__ W1, __half* __restrict__ BT1,
                                const float* __restrict__ W2, __half* __restrict__ BT2,
                                const float* __restrict__ W3, __half* __restrict__ BT3,
                                const float* __restrict__ W4, __half* __restrict__ BT4,
                                float* __restrict__ zero_as, int nzero) {
    int idx = blockIdx.x * 256 + threadIdx.x;
    if (idx < nx) { A[idx] = __float2half(X[idx]); return; }
    idx -= nx;
    if (idx < 131072) { convW_one(W1, BT1, idx, 256, 512); return; }
    idx -= 131072;
    if (idx < 262144) { convW_one(W2, BT2, idx, 512, 512); return; }
    idx -= 262144;
    if (idx < 131072) { convW_one(W3, BT3, idx, 512, 256); return; }
    idx -= 131072;
    if (idx < 32768)  { convW_one(W4, BT4, idx, 256, 64); return; }
    idx -= 32768;
    if (idx < nzero) zero_as[idx] = 0.f;
}

// ---------------------------------------------------------------------------
// fp16 MFMA GEMM: C = A_f16 x B_f16. BKK=64, 32 KB LDS (A|B), 32 MFMAs per
// barrier, XCD-aware 1-D swizzle, fused alpha epilogue, fp16 C.
// Bank swizzle: 8 chunks/row, XOR with row&7.
// ---------------------------------------------------------------------------
#define BM 128
#define BN 128
#define BKK 64

__launch_bounds__(256, 4)
static __global__ void gemm_mfma(const __half* __restrict__ A,
                                 const __half* __restrict__ B,
                                 __half* __restrict__ C, int M, int K, int N,
                                 int xcols, int mblocks,
                                 const float* __restrict__ asv,
                                 const float* __restrict__ adv,
                                 float* __restrict__ as_out,
                                 float* __restrict__ ad_out,
                                 int Hh, int Cc) {
    __shared__ __align__(16) __half lds[2 * BM * BKK];   // 32 KB
    const int tid  = threadIdx.x;
    const int lane = tid & 63;
    const int wave = tid >> 6;

    const int id = blockIdx.x;
    const int band = id / (8 * xcols);
    const int rem = id - band * 8 * xcols;
    const int band_rows = min(8, mblocks - band * 8);
    const int ry = rem % band_rows;
    const int rx = rem / band_rows;
    const int r0 = (band * 8 + ry) * BM;
    const int c0 = rx * BN;

    const int wm = (wave >> 1) * 64;
    const int wn = (wave & 1) * 64;
    const int q   = lane >> 4;        // 0..3
    const int m16 = lane & 15;

    floatx4 acc[4][4];
#pragma unroll
    for (int i = 0; i < 4; i++)
#pragma unroll
        for (int j = 0; j < 4; j++) acc[i][j] = {0.f, 0.f, 0.f, 0.f};

    char* ldsb = (char*)lds;

#pragma unroll 1
    for (int k0 = 0; k0 < K; k0 += BKK) {
        __syncthreads();
#pragma unroll
        for (int c = 0; c < 4; c++) {
            int slot = c * 256 + tid;      // 0..1023
            int row = slot >> 3;           // 0..127
            int gc  = (slot & 7) ^ (row & 7);
            gload16(A + (size_t)(r0 + row) * K + k0 + gc * 8,
                    ldsb + slot * 16);                       // A
            gload16(B + (size_t)(c0 + row) * K + k0 + gc * 8,
                    ldsb + 16384 + slot * 16);               // B
        }
        __syncthreads();
#pragma unroll
        for (int ks = 0; ks < 2; ks++) {
            f16x8 af[4], bf[4];
#pragma unroll
            for (int i = 0; i < 4; i++) {
                int row = wm + i * 16 + m16;
                int ch  = (q + ks * 4) ^ (row & 7);
                af[i] = *(const f16x8*)(ldsb + (row * 8 + ch) * 16);
            }
#pragma unroll
            for (int j = 0; j < 4; j++) {
                int row = wn + j * 16 + m16;
                int ch  = (q + ks * 4) ^ (row & 7);
                bf[j] = *(const f16x8*)(ldsb + 16384 + (row * 8 + ch) * 16);
            }
#pragma unroll
            for (int i = 0; i < 4; i++)
#pragma unroll
                for (int j = 0; j < 4; j++)
                    acc[i][j] = __builtin_amdgcn_mfma_f32_16x16x32_f16(
                        af[i], bf[j], acc[i][j], 0, 0, 0);
        }
    }
    // C store (fp16). C/D layout: col = lane&15, row = (lane>>4)*4 + reg
#pragma unroll
    for (int i = 0; i < 4; i++)
#pragma unroll
        for (int j = 0; j < 4; j++)
#pragma unroll
            for (int r = 0; r < 4; r++) {
                int row = r0 + wm + i * 16 + q * 4 + r;
                int col = c0 + wn + j * 16 + m16;
                if (row < M && col < N)
                    C[(size_t)row * N + col] = __float2half(acc[i][j][r]);
            }
    // fused alpha epilogue: wave's 64-col chunk is head-uniform (C in {64,128}).
    if (c0 + wn < N) {
        int head = (c0 + wn) / Cc;
#pragma unroll
        for (int i = 0; i < 4; i++)
#pragma unroll
            for (int r = 0; r < 4; r++) {
                float ps = 0.f, pd = 0.f;
#pragma unroll
                for (int j = 0; j < 4; j++) {
                    int c = c0 + wn + j * 16 + m16;
                    float v = acc[i][j][r];
                    ps = fmaf(v, asv[c], ps);
                    pd = fmaf(v, adv[c], pd);
                }
#pragma unroll
                for (int off = 1; off < 16; off <<= 1) {
                    ps += __shfl_xor(ps, off);
                    pd += __shfl_xor(pd, off);
                }
                if (m16 == 0) {
                    int row = r0 + wm + i * 16 + q * 4 + r;
                    if (row < M) {
                        atomicAdd(&as_out[(size_t)row * Hh + head], ps);
                        atomicAdd(&ad_out[(size_t)row * Hh + head], pd);
                    }
                }
            }
    }
}

// ---------------------------------------------------------------------------
// stats kernel: one wave/node. Pass 1: per-head online softmax (m, l) with
// LDS e-cache. Pass 2: materialize final per-edge weight exp(e-m)/l as fp16,
// HEAD-MAJOR layout w[h][Epad] (so gather groups read contiguous w).
// Epilogue zeroes next layer's as/ad ping-pong.
// ---------------------------------------------------------------------------
template <int H>
__launch_bounds__(256)
static __global__ void stats_kernel(const float* __restrict__ as_arr,
                                    const float* __restrict__ ad_arr,
                                    const int* __restrict__ row_ptr,
                                    const int* __restrict__ src_sorted,
                                    __half* __restrict__ w_arr, int Epad,
                                    float* __restrict__ znext_as,
                                    float* __restrict__ znext_ad, int n_nodes) {
    __shared__ float lds_e[4][DEG_CAP * H];
    int wave = threadIdx.x >> 6;
    int lane = threadIdx.x & 63;
    int n = blockIdx.x * 4 + wave;
    if (n >= n_nodes) return;
    int beg = row_ptr[n], end = row_ptr[n + 1];
    float* we = lds_e[wave];

    // ---- pass 1: per-head m, l; cache e in LDS ----
    float ad_h[H], m_h[H], l_h[H];
#pragma unroll
    for (int hh = 0; hh < H; hh++) {
        ad_h[hh] = ad_arr[(size_t)n * H + hh];
        m_h[hh] = -INFINITY;
        l_h[hh] = 0.f;
    }
    for (int base = beg; base < end; base += 64) {
        int j = base + lane;
        bool ok = j < end;
        float e_h[H];
        if (ok) {
            int s = src_sorted[j];
            if constexpr (H == 4) {
                float4 a = ((const float4*)as_arr)[s];
                e_h[0] = lrelu(a.x + ad_h[0]);
                e_h[1] = lrelu(a.y + ad_h[1]);
                e_h[2] = lrelu(a.z + ad_h[2]);
                e_h[3] = lrelu(a.w + ad_h[3]);
            } else {
                e_h[0] = lrelu(as_arr[s] + ad_h[0]);
            }
            int idx = j - beg;
            if (idx < DEG_CAP) {
                if constexpr (H == 4) {
                    *(float4*)&we[idx * 4] = make_float4(e_h[0], e_h[1], e_h[2], e_h[3]);
                } else {
                    we[idx] = e_h[0];
                }
            }
        } else {
#pragma unroll
            for (int hh = 0; hh < H; hh++) e_h[hh] = -INFINITY;
        }
#pragma unroll
        for (int hh = 0; hh < H; hh++) {
            float cm = e_h[hh];
#pragma unroll
            for (int off = 1; off < 64; off <<= 1) cm = fmaxf(cm, __shfl_xor(cm, off));
            float newm = fmaxf(m_h[hh], cm);
            float p = ok ? __expf(e_h[hh] - newm) : 0.f;
#pragma unroll
            for (int off = 1; off < 64; off <<= 1) p += __shfl_xor(p, off);
            l_h[hh] = l_h[hh] * __expf(m_h[hh] - newm) + p;
            m_h[hh] = newm;
        }
    }
    float inv_h[H];
#pragma unroll
    for (int hh = 0; hh < H; hh++) inv_h[hh] = 1.f / l_h[hh];

    // ---- pass 2: write per-edge fp16 weights, head-major (streaming) ----
    unsigned short* wp = (unsigned short*)w_arr;
    for (int base = beg; base < end; base += 64) {
        int j = base + lane;
        if (j < end) {
            int idx = j - beg;
            float e_h[H];
            if (idx < DEG_CAP) {
                if constexpr (H == 4) {
                    float4 t = *(float4*)&we[idx * 4];
                    e_h[0] = t.x; e_h[1] = t.y; e_h[2] = t.z; e_h[3] = t.w;
                } else {
                    e_h[0] = we[idx];
                }
            } else {
                int s = src_sorted[j];
                if constexpr (H == 4) {
                    float4 a = ((const float4*)as_arr)[s];
                    e_h[0] = lrelu(a.x + ad_h[0]);
                    e_h[1] = lrelu(a.y + ad_h[1]);
                    e_h[2] = lrelu(a.z + ad_h[2]);
                    e_h[3] = lrelu(a.w + ad_h[3]);
                } else {
                    e_h[0] = lrelu(as_arr[s] + ad_h[0]);
                }
            }
#pragma unroll
            for (int hh = 0; hh < H; hh++)
                __builtin_nontemporal_store(
                    __half_as_ushort(__float2half(
                        __expf(e_h[hh] - m_h[hh]) * inv_h[hh])),
                    wp + (size_t)hh * Epad + j);
        }
    }

    if (znext_as != nullptr && lane == 0) {
        if constexpr (H == 4) {
            *(float4*)&znext_as[(size_t)n * 4] = make_float4(0.f, 0.f, 0.f, 0.f);
            *(float4*)&znext_ad[(size_t)n * 4] = make_float4(0.f, 0.f, 0.f, 0.f);
        } else {
            znext_as[n] = 0.f;
            znext_ad[n] = 0.f;
        }
    }
}

// ---------------------------------------------------------------------------
// group-per-node sliced gather with degree-sorted node assignment.
// slice = blockIdx % NSLICE -> XCD affinity (64-col slice = 3.84 MB, L2-
// resident). lane = g*8+cg: group g (8 lanes) owns node node_order[idx];
// lane cg owns cols colbase = slice*64 + cg*8 (16B). acc lane-private ->
// no cross-lane reduction. src/w are REGULAR loads (L2-cached; R19's
// nontemporal 2-4B touches caused a line-refetch storm, FETCH 58->100MB).
// Degree-sorted order gives each wave 8 nodes of adjacent degree rank ->
// loop trip ~= avg degree (R19's VALU 25% divergence fix).
// ---------------------------------------------------------------------------
template <int H, int C, bool F16OUT>
__launch_bounds__(256)
static __global__ void gather_slice(const __half* __restrict__ h,
                                    const __half* __restrict__ w_arr,
                                    const int* __restrict__ row_ptr,
                                    const int* __restrict__ src_sorted,
                                    const int* __restrict__ node_order,
                                    const float* __restrict__ bias,
                                    float* __restrict__ outf,
                                    __half* __restrict__ outh,
                                    int n_nodes, int Epad) {
    constexpr int K = H * C;
    constexpr int NSLICE = K / 64;
    const int wave = threadIdx.x >> 6;
    const int lane = threadIdx.x & 63;
    const int g  = lane >> 3;        // node-group 0..7
    const int cg = lane & 7;         // col-lane 0..7 (8 cols, 16B)
    const int slice = blockIdx.x % NSLICE;
    const int group = blockIdx.x / NSLICE;
    const int colbase = slice * 64 + cg * 8;
    const int head = (slice * 64) / C;   // wave-uniform (64 | C)
    const unsigned short* wp = (const unsigned short*)w_arr + (size_t)head * Epad;

    // per-lane bias (8 cols)
    float bloc[8];
    {
        float4 b0 = *(const float4*)(bias + colbase);
        float4 b1 = *(const float4*)(bias + colbase + 4);
        bloc[0] = b0.x; bloc[1] = b0.y; bloc[2] = b0.z; bloc[3] = b0.w;
        bloc[4] = b1.x; bloc[5] = b1.y; bloc[6] = b1.z; bloc[7] = b1.w;
    }

    const int idx = (group * 4 + wave) * 8 + g;   // 8 nodes per wave
    const bool valid = idx < n_nodes;
    int n = 0, beg = 0, end = 0;
    if (valid) {
        n = node_order[idx];                       // degree-rank ordered
        beg = row_ptr[n];
        end = row_ptr[n + 1];
    }

    float acc[8];
#pragma unroll
    for (int r = 0; r < 8; r++) acc[r] = 0.f;

    int j = beg;
    for (; j + 1 < end; j += 2) {     // 2 independent edges in flight
        int s0 = src_sorted[j];
        int s1 = src_sorted[j + 1];
        float w0 = ushort2floath(wp[j]);
        float w1 = ushort2floath(wp[j + 1]);
        float4 r0 = *(const float4*)(h + (size_t)s0 * K + colbase);
        float4 r1 = *(const float4*)(h + (size_t)s1 * K + colbase);
        const __half* h0 = (const __half*)&r0;
        const __half* h1 = (const __half*)&r1;
#pragma unroll
        for (int r = 0; r < 8; r++)
            acc[r] = fmaf(w0, __half2float(h0[r]), acc[r]);
#pragma unroll
        for (int r = 0; r < 8; r++)
            acc[r] = fmaf(w1, __half2float(h1[r]), acc[r]);
    }
    if (j < end) {
        int s0 = src_sorted[j];
        float w0 = ushort2floath(wp[j]);
        float4 r0 = *(const float4*)(h + (size_t)s0 * K + colbase);
        const __half* h0 = (const __half*)&r0;
#pragma unroll
        for (int r = 0; r < 8; r++)
            acc[r] = fmaf(w0, __half2float(h0[r]), acc[r]);
    }

    if (valid) {
        float v[8];
#pragma unroll
        for (int r = 0; r < 8; r++) v[r] = fmaxf(acc[r] + bloc[r], 0.f);
        if constexpr (F16OUT) {
            usv8 o;
#pragma unroll
            for (int r = 0; r < 8; r++)
                o[r] = __half_as_ushort(__float2half(v[r]));
            __builtin_nontemporal_store(
                o, (usv8*)((unsigned short*)outh + (size_t)n * K + colbase));
        } else {
            floatx4 o0 = {v[0], v[1], v[2], v[3]};
            floatx4 o1 = {v[4], v[5], v[6], v[7]};
            __builtin_nontemporal_store(
                o0, (floatx4*)(outf + (size_t)n * K + colbase));
            __builtin_nontemporal_store(
                o1, (floatx4*)(outf + (size_t)n * K + colbase + 4));
        }
    }
}

// ---------------------------------------------------------------------------

static inline size_t align_up(size_t x) { return (x + 255) & ~(size_t)255; }

extern "C" void kernel_launch(void* const* d_in, const int* in_sizes, int n_in,
                              void* d_out, int out_size, void* d_ws, size_t ws_size,
                              hipStream_t stream) {
    const float* x   = (const float*)d_in[0];
    const int*   ei  = (const int*)d_in[1];
    const float* W1  = (const float*)d_in[2];
    const float* a1s = (const float*)d_in[3];
    const float* a1d = (const float*)d_in[4];
    const float* b1  = (const float*)d_in[5];
    const float* W2  = (const float*)d_in[6];
    const float* a2s = (const float*)d_in[7];
    const float* a2d = (const float*)d_in[8];
    const float* b2  = (const float*)d_in[9];
    const float* W3  = (const float*)d_in[10];
    const float* a3s = (const float*)d_in[11];
    const float* a3d = (const float*)d_in[12];
    const float* b3  = (const float*)d_in[13];
    const float* W4  = (const float*)d_in[14];
    const float* a4s = (const float*)d_in[15];
    const float* a4d = (const float*)d_in[16];
    const float* b4  = (const float*)d_in[17];

    const int n  = in_sizes[0] / 256;    // 30000
    const int e0 = in_sizes[1] / 2;      // 480000
    const int et = e0 + n;
    const int Mpad = ((n + 127) / 128) * 128;   // 30080
    const int Epad = ((et + 255) / 256) * 256;  // head-major w plane stride

    // workspace layout (~104 MB)
    char* w = (char*)d_ws;
    __half* bufA = (__half*)w;                   w += align_up((size_t)Mpad * 512 * 2);
    __half* bufB = (__half*)w;                   w += align_up((size_t)Mpad * 512 * 2);
    __half* hbuf = (__half*)w;                   w += align_up((size_t)Mpad * 512 * 2);
    __half* WT1 = (__half*)w;                    w += align_up((size_t)512 * 256 * 2);
    __half* WT2 = (__half*)w;                    w += align_up((size_t)512 * 512 * 2);
    __half* WT3 = (__half*)w;                    w += align_up((size_t)256 * 512 * 2);
    __half* WT4 = (__half*)w;                    w += align_up((size_t)128 * 256 * 2);
    float* asA = (float*)w;                      w += align_up((size_t)n * 4 * 4);
    float* adA = (float*)w;                      w += align_up((size_t)n * 4 * 4);
    float* asB = (float*)w;                      w += align_up((size_t)n * 4 * 4);
    float* adB = (float*)w;                      w += align_up((size_t)n * 4 * 4);
    int* row_ptr = (int*)w;                      w += align_up((size_t)(n + 1) * 4);
    int* counts  = (int*)w;                      w += align_up((size_t)n * 4);
    int* cursor  = (int*)w;                      w += align_up((size_t)n * 4);
    int* src_sorted = (int*)w;                   w += align_up((size_t)et * 4);
    __half* wbuf = (__half*)w;                   w += align_up((size_t)Epad * 4 * 2);
    int* node_order = (int*)w;                   w += align_up((size_t)n * 4);
    int* dhist = (int*)w;                        w += align_up((size_t)DBUCKETS * 4);
    int* drp   = (int*)w;                        w += align_up((size_t)(DBUCKETS + 1) * 4);
    int* dcur  = (int*)w;                        w += align_up((size_t)DBUCKETS * 4);
    (void)ws_size;

    dim3 blk(256);
    int nodeblocks = (n + 3) / 4;
    int ggrp = (n + 31) / 32;   // gather groups: 4 waves x 8 nodes per block

    // ---- CSR build ----
    zero_int<<<(n + 255) / 256, 256, 0, stream>>>(counts, n);
    hist_kernel<<<(et + 255) / 256, 256, 0, stream>>>(ei, e0, n, counts);
    scan_kernel<<<1, 1024, 0, stream>>>(counts, row_ptr, cursor, n);
    scatter_kernel<<<(et + 255) / 256, 256, 0, stream>>>(ei, e0, n, cursor, src_sorted);

    // ---- degree counting sort (balances gather waves) ----
    zero_int<<<(DBUCKETS + 255) / 256, 256, 0, stream>>>(dhist, DBUCKETS);
    deg_hist_kernel<<<(n + 255) / 256, 256, 0, stream>>>(counts, n, dhist);
    scan_kernel<<<1, 1024, 0, stream>>>(dhist, drp, dcur, DBUCKETS);
    order_scatter_kernel<<<(n + 255) / 256, 256, 0, stream>>>(counts, n, dcur, node_order);

    // ---- fused conversion prologue (x + 4 weights + as/ad zero) ----
    const int nx = n * 256;
    conv_all<<<(nx + 557056 + n * 8 + 255) / 256, blk, 0, stream>>>(
        x, bufA, nx, W1, WT1, W2, WT2, W3, WT3, W4, WT4, asA, n * 8);

    const int mblocks = Mpad / 128;   // 235

    // ---- Layer 1: K=256 -> N=512 (4 heads x 128) ----
    gemm_mfma<<<dim3(4 * mblocks), blk, 0, stream>>>(bufA, WT1, hbuf, n, 256, 512, 4, mblocks,
                                                     a1s, a1d, asA, adA, 4, 128);
    stats_kernel<4><<<nodeblocks, blk, 0, stream>>>(asA, adA, row_ptr, src_sorted, wbuf, Epad, asB, adB, n);
    gather_slice<4, 128, true><<<dim3(8 * ggrp), blk, 0, stream>>>(
        hbuf, wbuf, row_ptr, src_sorted, node_order, b1, nullptr, bufB, n, Epad);

    // ---- Layer 2: K=512 -> N=512 ----
    gemm_mfma<<<dim3(4 * mblocks), blk, 0, stream>>>(bufB, WT2, hbuf, n, 512, 512, 4, mblocks,
                                                     a2s, a2d, asB, adB, 4, 128);
    stats_kernel<4><<<nodeblocks, blk, 0, stream>>>(asB, adB, row_ptr, src_sorted, wbuf, Epad, asA, adA, n);
    gather_slice<4, 128, true><<<dim3(8 * ggrp), blk, 0, stream>>>(
        hbuf, wbuf, row_ptr, src_sorted, node_order, b2, nullptr, bufA, n, Epad);

    // ---- Layer 3: K=512 -> N=256 (4 heads x 64) ----
    gemm_mfma<<<dim3(2 * mblocks), blk, 0, stream>>>(bufA, WT3, hbuf, n, 512, 256, 2, mblocks,
                                                     a3s, a3d, asA, adA, 4, 64);
    stats_kernel<4><<<nodeblocks, blk, 0, stream>>>(asA, adA, row_ptr, src_sorted, wbuf, Epad, asB, adB, n);
    gather_slice<4, 64, true><<<dim3(4 * ggrp), blk, 0, stream>>>(
        hbuf, wbuf, row_ptr, src_sorted, node_order, b3, nullptr, bufB, n, Epad);

    // ---- Layer 4: K=256 -> N=64, 1 head ----
    gemm_mfma<<<dim3(1 * mblocks), blk, 0, stream>>>(bufB, WT4, hbuf, n, 256, 64, 1, mblocks,
                                                     a4s, a4d, asB, adB, 1, 64);
    stats_kernel<1><<<nodeblocks, blk, 0, stream>>>(asB, adB, row_ptr, src_sorted, wbuf, Epad, nullptr, nullptr, n);
    gather_slice<1, 64, false><<<dim3(1 * ggrp), blk, 0, stream>>>(
        hbuf, wbuf, row_ptr, src_sorted, node_order, b4, (float*)d_out, nullptr, n, Epad);
}

// Round 22
// 573.589 us; speedup vs baseline: 1.3600x; 1.3600x over previous
//
#include <hip/hip_runtime.h>
#include <hip/hip_fp16.h>
#include <math.h>

// ---------------------------------------------------------------------------
// GAT 4-layer forward.  (R21 = R16 revert + 8-edge gather unroll; resubmit
// after broker timeout — never measured.)
//   Slicing arc post-mortem (R17-R20, all measured): sliced agg best-case =
//   stats 8us + gather >=85us per layer vs R16's FUSED agg at 77us/layer
//   doing both. Slice FETCH savings (238->58MB) never became time: fused agg
//   is latency-bound (HBM 45%, VALU 42%, occ 62%, nothing saturated), not
//   BW-bound. R20's degree-sort scatter alone cost 84us (position-returning
//   atomics on ~40 hot buckets serialize). Decision rule: revert to R16.
//   R21's single variable: agg pass-2 unrolled 4->8 edges (8 independent
//   16B h-loads in flight per wave, 2x ILP) to attack the measured latency
//   bound. Everything else identical to R16 (measured 558.6us).
// ---------------------------------------------------------------------------

typedef __attribute__((ext_vector_type(8))) _Float16 f16x8;
typedef __attribute__((ext_vector_type(4))) float floatx4;
typedef __attribute__((ext_vector_type(8))) unsigned short usv8;
typedef __attribute__((ext_vector_type(4))) unsigned short usv4;

#define DEG_CAP 256

__device__ __forceinline__ float lrelu(float e) {
    return (e > 0.f) ? e : 0.2f * e;
}
__device__ __forceinline__ void gload16(const void* g, void* l) {
    __builtin_amdgcn_global_load_lds(
        (const __attribute__((address_space(1))) void*)g,
        (__attribute__((address_space(3))) void*)l, 16, 0, 0);
}

// ---------------------------------------------------------------------------
// CSR build
// ---------------------------------------------------------------------------
static __global__ void zero_int(int* __restrict__ p, int n) {
    int i = blockIdx.x * blockDim.x + threadIdx.x;
    if (i < n) p[i] = 0;
}

static __global__ void hist_kernel(const int* __restrict__ ei, int e0, int n_nodes,
                                   int* __restrict__ counts) {
    int e = blockIdx.x * blockDim.x + threadIdx.x;
    int et = e0 + n_nodes;
    if (e >= et) return;
    int d = (e < e0) ? ei[e0 + e] : (e - e0);
    atomicAdd(&counts[d], 1);
}

static __global__ void scan_kernel(const int* __restrict__ counts,
                                   int* __restrict__ row_ptr,
                                   int* __restrict__ cursor, int n) {
    __shared__ int sdata[1024];
    int tid = threadIdx.x;
    int per = (n + 1023) / 1024;
    int start = tid * per;
    int stop = min(start + per, n);
    if (start > n) start = n;
    int s = 0;
    for (int i = start; i < stop; i++) s += counts[i];
    sdata[tid] = s;
    __syncthreads();
    for (int off = 1; off < 1024; off <<= 1) {
        int t = (tid >= off) ? sdata[tid - off] : 0;
        __syncthreads();
        sdata[tid] += t;
        __syncthreads();
    }
    int run = sdata[tid] - s;
    for (int i = start; i < stop; i++) {
        row_ptr[i] = run;
        cursor[i] = run;
        run += counts[i];
    }
    if (stop == n) row_ptr[n] = run;
}

static __global__ void scatter_kernel(const int* __restrict__ ei, int e0, int n_nodes,
                                      int* __restrict__ cursor,
                                      int* __restrict__ src_sorted) {
    int e = blockIdx.x * blockDim.x + threadIdx.x;
    int et = e0 + n_nodes;
    if (e >= et) return;
    int s, d;
    if (e < e0) { s = ei[e]; d = ei[e0 + e]; } else { s = e - e0; d = s; }
    int pos = atomicAdd(&cursor[d], 1);
    src_sorted[pos] = s;
}

// ---------------------------------------------------------------------------
// fused conversion prologue: x -> fp16 A, 4x W -> fp16 W^T, zero as/ad.
// ---------------------------------------------------------------------------
__device__ __forceinline__ void convW_one(const float* W, __half* BT,
                                          int idx, int K, int N) {
    int n = idx / K, k = idx % K;
    float v = (n < N) ? W[(size_t)k * N + n] : 0.f;
    BT[(size_t)n * K + k] = __float2half(v);
}

static __global__ void conv_all(const float* __restrict__ X, __half* __restrict__ A, int nx,
                                const float* __restrict__ W1, __half* __restrict__ BT1,
                                const float* __restrict__ W2, __half* __restrict__ BT2,
                                const float* __restrict__ W3, __half* __restrict__ BT3,
                                const float* __restrict__ W4, __half* __restrict__ BT4,
                                float* __restrict__ zero_as, int nzero) {
    int idx = blockIdx.x * 256 + threadIdx.x;
    if (idx < nx) { A[idx] = __float2half(X[idx]); return; }
    idx -= nx;
    if (idx < 131072) { convW_one(W1, BT1, idx, 256, 512); return; }
    idx -= 131072;
    if (idx < 262144) { convW_one(W2, BT2, idx, 512, 512); return; }
    idx -= 262144;
    if (idx < 131072) { convW_one(W3, BT3, idx, 512, 256); return; }
    idx -= 131072;
    if (idx < 32768)  { convW_one(W4, BT4, idx, 256, 64); return; }
    idx -= 32768;
    if (idx < nzero) zero_as[idx] = 0.f;
}

// ---------------------------------------------------------------------------
// fp16 MFMA GEMM: C = A_f16 x B_f16. BKK=64, 32 KB LDS (A|B), 32 MFMAs per
// barrier, XCD-aware 1-D swizzle, fused alpha epilogue, fp16 C.
// Bank swizzle: 8 chunks/row, XOR with row&7.
// ---------------------------------------------------------------------------
#define BM 128
#define BN 128
#define BKK 64

__launch_bounds__(256, 4)
static __global__ void gemm_mfma(const __half* __restrict__ A,
                                 const __half* __restrict__ B,
                                 __half* __restrict__ C, int M, int K, int N,
                                 int xcols, int mblocks,
                                 const float* __restrict__ asv,
                                 const float* __restrict__ adv,
                                 float* __restrict__ as_out,
                                 float* __restrict__ ad_out,
                                 int Hh, int Cc) {
    __shared__ __align__(16) __half lds[2 * BM * BKK];   // 32 KB
    const int tid  = threadIdx.x;
    const int lane = tid & 63;
    const int wave = tid >> 6;

    const int id = blockIdx.x;
    const int band = id / (8 * xcols);
    const int rem = id - band * 8 * xcols;
    const int band_rows = min(8, mblocks - band * 8);
    const int ry = rem % band_rows;
    const int rx = rem / band_rows;
    const int r0 = (band * 8 + ry) * BM;
    const int c0 = rx * BN;

    const int wm = (wave >> 1) * 64;
    const int wn = (wave & 1) * 64;
    const int q   = lane >> 4;        // 0..3
    const int m16 = lane & 15;

    floatx4 acc[4][4];
#pragma unroll
    for (int i = 0; i < 4; i++)
#pragma unroll
        for (int j = 0; j < 4; j++) acc[i][j] = {0.f, 0.f, 0.f, 0.f};

    char* ldsb = (char*)lds;

#pragma unroll 1
    for (int k0 = 0; k0 < K; k0 += BKK) {
        __syncthreads();
#pragma unroll
        for (int c = 0; c < 4; c++) {
            int slot = c * 256 + tid;      // 0..1023
            int row = slot >> 3;           // 0..127
            int gc  = (slot & 7) ^ (row & 7);
            gload16(A + (size_t)(r0 + row) * K + k0 + gc * 8,
                    ldsb + slot * 16);                       // A
            gload16(B + (size_t)(c0 + row) * K + k0 + gc * 8,
                    ldsb + 16384 + slot * 16);               // B
        }
        __syncthreads();
#pragma unroll
        for (int ks = 0; ks < 2; ks++) {
            f16x8 af[4], bf[4];
#pragma unroll
            for (int i = 0; i < 4; i++) {
                int row = wm + i * 16 + m16;
                int ch  = (q + ks * 4) ^ (row & 7);
                af[i] = *(const f16x8*)(ldsb + (row * 8 + ch) * 16);
            }
#pragma unroll
            for (int j = 0; j < 4; j++) {
                int row = wn + j * 16 + m16;
                int ch  = (q + ks * 4) ^ (row & 7);
                bf[j] = *(const f16x8*)(ldsb + 16384 + (row * 8 + ch) * 16);
            }
#pragma unroll
            for (int i = 0; i < 4; i++)
#pragma unroll
                for (int j = 0; j < 4; j++)
                    acc[i][j] = __builtin_amdgcn_mfma_f32_16x16x32_f16(
                        af[i], bf[j], acc[i][j], 0, 0, 0);
        }
    }
    // C store (fp16). C/D layout: col = lane&15, row = (lane>>4)*4 + reg
#pragma unroll
    for (int i = 0; i < 4; i++)
#pragma unroll
        for (int j = 0; j < 4; j++)
#pragma unroll
            for (int r = 0; r < 4; r++) {
                int row = r0 + wm + i * 16 + q * 4 + r;
                int col = c0 + wn + j * 16 + m16;
                if (row < M && col < N)
                    C[(size_t)row * N + col] = __float2half(acc[i][j][r]);
            }
    // fused alpha epilogue: wave's 64-col chunk is head-uniform (C in {64,128}).
    if (c0 + wn < N) {
        int head = (c0 + wn) / Cc;
#pragma unroll
        for (int i = 0; i < 4; i++)
#pragma unroll
            for (int r = 0; r < 4; r++) {
                float ps = 0.f, pd = 0.f;
#pragma unroll
                for (int j = 0; j < 4; j++) {
                    int c = c0 + wn + j * 16 + m16;
                    float v = acc[i][j][r];
                    ps = fmaf(v, asv[c], ps);
                    pd = fmaf(v, adv[c], pd);
                }
#pragma unroll
                for (int off = 1; off < 16; off <<= 1) {
                    ps += __shfl_xor(ps, off);
                    pd += __shfl_xor(pd, off);
                }
                if (m16 == 0) {
                    int row = r0 + wm + i * 16 + q * 4 + r;
                    if (row < M) {
                        atomicAdd(&as_out[(size_t)row * Hh + head], ps);
                        atomicAdd(&ad_out[(size_t)row * Hh + head], pd);
                    }
                }
            }
    }
}

// ---------------------------------------------------------------------------
// gather helper: acc[r] += w * h_fp16[off+r]
// ---------------------------------------------------------------------------
template <int R>
__device__ __forceinline__ void accum_row(const __half* hptr, size_t off, float w,
                                          float* acc) {
    const __half* p = hptr + off;
    if constexpr (R == 8) {
        float4 raw = *(const float4*)p;          // 8 halves, one dwordx4
        const __half* hv = (const __half*)&raw;
#pragma unroll
        for (int r = 0; r < 8; r++) acc[r] = fmaf(__half2float(hv[r]), w, acc[r]);
    } else if constexpr (R == 4) {
        float2 raw = *(const float2*)p;
        const __half* hv = (const __half*)&raw;
#pragma unroll
        for (int r = 0; r < 4; r++) acc[r] = fmaf(__half2float(hv[r]), w, acc[r]);
    } else {
        acc[0] = fmaf(__half2float(*p), w, acc[0]);
    }
}

// ---------------------------------------------------------------------------
// aggregation: one wave/node. Pass 1 caches e in LDS (DEG_CAP), reduces m,l.
// Pass 2: 8-edge unroll (R21: was 4; agg is latency-bound per R16 counters,
// deeper unroll doubles in-flight h-loads/wave), w from cached e, fp16
// gather. Output fp16 (next A) or fp32 (final). Epilogue zeroes next
// layer's as/ad ping-pong.
// ---------------------------------------------------------------------------
template <int H, int C, bool F16OUT>
__launch_bounds__(256)
static __global__ void agg_kernel(const __half* __restrict__ h,
                                  const float* __restrict__ as_arr,
                                  const float* __restrict__ ad_arr,
                                  const int* __restrict__ row_ptr,
                                  const int* __restrict__ src_sorted,
                                  const float* __restrict__ bias,
                                  float* __restrict__ outf,
                                  __half* __restrict__ outh,
                                  float* __restrict__ znext_as,
                                  float* __restrict__ znext_ad, int n_nodes) {
    constexpr int R = H * C / 64;
    constexpr int G = 64 / H;
    constexpr int K = H * C;
    __shared__ float lds_e[4][DEG_CAP * H];
    int wave = threadIdx.x >> 6;
    int lane = threadIdx.x & 63;
    int n = blockIdx.x * 4 + wave;
    if (n >= n_nodes) return;
    int beg = row_ptr[n], end = row_ptr[n + 1];
    float* we = lds_e[wave];

    // ---- pass 1: per-head m, l; cache e in LDS ----
    float ad_h[H], m_h[H], l_h[H];
#pragma unroll
    for (int hh = 0; hh < H; hh++) {
        ad_h[hh] = ad_arr[(size_t)n * H + hh];
        m_h[hh] = -INFINITY;
        l_h[hh] = 0.f;
    }
    for (int base = beg; base < end; base += 64) {
        int j = base + lane;
        bool ok = j < end;
        float e_h[H];
        if (ok) {
            int s = src_sorted[j];
            if constexpr (H == 4) {
                float4 a = ((const float4*)as_arr)[s];
                e_h[0] = lrelu(a.x + ad_h[0]);
                e_h[1] = lrelu(a.y + ad_h[1]);
                e_h[2] = lrelu(a.z + ad_h[2]);
                e_h[3] = lrelu(a.w + ad_h[3]);
            } else {
                e_h[0] = lrelu(as_arr[s] + ad_h[0]);
            }
            int idx = j - beg;
            if (idx < DEG_CAP) {
                if constexpr (H == 4) {
                    *(float4*)&we[idx * 4] = make_float4(e_h[0], e_h[1], e_h[2], e_h[3]);
                } else {
                    we[idx] = e_h[0];
                }
            }
        } else {
#pragma unroll
            for (int hh = 0; hh < H; hh++) e_h[hh] = -INFINITY;
        }
#pragma unroll
        for (int hh = 0; hh < H; hh++) {
            float cm = e_h[hh];
#pragma unroll
            for (int off = 1; off < 64; off <<= 1) cm = fmaxf(cm, __shfl_xor(cm, off));
            float newm = fmaxf(m_h[hh], cm);
            float p = ok ? __expf(e_h[hh] - newm) : 0.f;
#pragma unroll
            for (int off = 1; off < 64; off <<= 1) p += __shfl_xor(p, off);
            l_h[hh] = l_h[hh] * __expf(m_h[hh] - newm) + p;
            m_h[hh] = newm;
        }
    }
    int myh = lane / G;
    float mm, adm, inv;
    if constexpr (H == 4) {
        mm  = m_h[0];  mm  = (myh == 1) ? m_h[1] : mm;  mm  = (myh == 2) ? m_h[2] : mm;  mm  = (myh == 3) ? m_h[3] : mm;
        float ll = l_h[0]; ll = (myh == 1) ? l_h[1] : ll; ll = (myh == 2) ? l_h[2] : ll; ll = (myh == 3) ? l_h[3] : ll;
        adm = ad_h[0]; adm = (myh == 1) ? ad_h[1] : adm; adm = (myh == 2) ? ad_h[2] : adm; adm = (myh == 3) ? ad_h[3] : adm;
        inv = 1.f / ll;
    } else {
        mm = m_h[0]; adm = ad_h[0]; inv = 1.f / l_h[0];
    }

    // ---- pass 2: gather, w from cached e (8-edge unroll for ILP) ----
    float acc[R];
#pragma unroll
    for (int r = 0; r < R; r++) acc[r] = 0.f;

    int j = beg;
    for (; j + 7 < end; j += 8) {
        int i0 = j - beg;
        int s8[8];
#pragma unroll
        for (int u = 0; u < 8; u++) s8[u] = src_sorted[j + u];
        float e8[8];
        if (i0 + 7 < DEG_CAP) {
#pragma unroll
            for (int u = 0; u < 8; u++) e8[u] = we[(i0 + u) * H + myh];
        } else {
#pragma unroll
            for (int u = 0; u < 8; u++)
                e8[u] = lrelu(as_arr[(size_t)s8[u] * H + myh] + adm);
        }
        float w8[8];
#pragma unroll
        for (int u = 0; u < 8; u++) w8[u] = __expf(e8[u] - mm) * inv;
#pragma unroll
        for (int u = 0; u < 8; u++)
            accum_row<R>(h, (size_t)s8[u] * K + lane * R, w8[u], acc);
    }
    for (; j + 3 < end; j += 4) {
        int i0 = j - beg;
        int s0 = src_sorted[j];
        int s1 = src_sorted[j + 1];
        int s2 = src_sorted[j + 2];
        int s3 = src_sorted[j + 3];
        float e0, e1, e2, e3;
        if (i0 + 3 < DEG_CAP) {
            e0 = we[(i0 + 0) * H + myh];
            e1 = we[(i0 + 1) * H + myh];
            e2 = we[(i0 + 2) * H + myh];
            e3 = we[(i0 + 3) * H + myh];
        } else {
            e0 = lrelu(as_arr[(size_t)s0 * H + myh] + adm);
            e1 = lrelu(as_arr[(size_t)s1 * H + myh] + adm);
            e2 = lrelu(as_arr[(size_t)s2 * H + myh] + adm);
            e3 = lrelu(as_arr[(size_t)s3 * H + myh] + adm);
        }
        float w0 = __expf(e0 - mm) * inv;
        float w1 = __expf(e1 - mm) * inv;
        float w2 = __expf(e2 - mm) * inv;
        float w3 = __expf(e3 - mm) * inv;
        accum_row<R>(h, (size_t)s0 * K + lane * R, w0, acc);
        accum_row<R>(h, (size_t)s1 * K + lane * R, w1, acc);
        accum_row<R>(h, (size_t)s2 * K + lane * R, w2, acc);
        accum_row<R>(h, (size_t)s3 * K + lane * R, w3, acc);
    }
    for (; j < end; j++) {
        int i0 = j - beg;
        int s0 = src_sorted[j];
        float e0 = (i0 < DEG_CAP) ? we[i0 * H + myh]
                                  : lrelu(as_arr[(size_t)s0 * H + myh] + adm);
        float w0 = __expf(e0 - mm) * inv;
        accum_row<R>(h, (size_t)s0 * K + lane * R, w0, acc);
    }

    // ---- epilogue: bias + relu; zero next layer's as/ad ----
    if (znext_as != nullptr && lane == 0) {
        if constexpr (H == 4) {
            *(float4*)&znext_as[(size_t)n * 4] = make_float4(0.f, 0.f, 0.f, 0.f);
            *(float4*)&znext_ad[(size_t)n * 4] = make_float4(0.f, 0.f, 0.f, 0.f);
        } else {
            znext_as[n] = 0.f;
            znext_ad[n] = 0.f;
        }
    }
    float vout[R];
#pragma unroll
    for (int r = 0; r < R; r++)
        vout[r] = fmaxf(acc[r] + bias[lane * R + r], 0.f);

    if constexpr (F16OUT) {
        unsigned short hv[R];
#pragma unroll
        for (int r = 0; r < R; r++)
            hv[r] = __half_as_ushort(__float2half(vout[r]));
        size_t base = (size_t)n * K + lane * R;
        if constexpr (R == 8) {
            usv8 v = {hv[0], hv[1], hv[2], hv[3], hv[4], hv[5], hv[6], hv[7]};
            *(usv8*)((unsigned short*)outh + base) = v;
        } else if constexpr (R == 4) {
            usv4 v = {hv[0], hv[1], hv[2], hv[3]};
            *(usv4*)((unsigned short*)outh + base) = v;
        } else {
#pragma unroll
            for (int r = 0; r < R; r++) ((unsigned short*)outh)[base + r] = hv[r];
        }
    } else {
#pragma unroll
        for (int r = 0; r < R; r++)
            outf[(size_t)n * K + lane * R + r] = vout[r];
    }
}

// ---------------------------------------------------------------------------

static inline size_t align_up(size_t x) { return (x + 255) & ~(size_t)255; }

extern "C" void kernel_launch(void* const* d_in, const int* in_sizes, int n_in,
                              void* d_out, int out_size, void* d_ws, size_t ws_size,
                              hipStream_t stream) {
    const float* x   = (const float*)d_in[0];
    const int*   ei  = (const int*)d_in[1];
    const float* W1  = (const float*)d_in[2];
    const float* a1s = (const float*)d_in[3];
    const float* a1d = (const float*)d_in[4];
    const float* b1  = (const float*)d_in[5];
    const float* W2  = (const float*)d_in[6];
    const float* a2s = (const float*)d_in[7];
    const float* a2d = (const float*)d_in[8];
    const float* b2  = (const float*)d_in[9];
    const float* W3  = (const float*)d_in[10];
    const float* a3s = (const float*)d_in[11];
    const float* a3d = (const float*)d_in[12];
    const float* b3  = (const float*)d_in[13];
    const float* W4  = (const float*)d_in[14];
    const float* a4s = (const float*)d_in[15];
    const float* a4d = (const float*)d_in[16];
    const float* b4  = (const float*)d_in[17];

    const int n  = in_sizes[0] / 256;    // 30000
    const int e0 = in_sizes[1] / 2;      // 480000
    const int et = e0 + n;
    const int Mpad = ((n + 127) / 128) * 128;   // 30080

    // workspace layout (~100 MB)
    char* w = (char*)d_ws;
    __half* bufA = (__half*)w;                   w += align_up((size_t)Mpad * 512 * 2);
    __half* bufB = (__half*)w;                   w += align_up((size_t)Mpad * 512 * 2);
    __half* hbuf = (__half*)w;                   w += align_up((size_t)Mpad * 512 * 2);
    __half* WT1 = (__half*)w;                    w += align_up((size_t)512 * 256 * 2);
    __half* WT2 = (__half*)w;                    w += align_up((size_t)512 * 512 * 2);
    __half* WT3 = (__half*)w;                    w += align_up((size_t)256 * 512 * 2);
    __half* WT4 = (__half*)w;                    w += align_up((size_t)128 * 256 * 2);
    float* asA = (float*)w;                      w += align_up((size_t)n * 4 * 4);
    float* adA = (float*)w;                      w += align_up((size_t)n * 4 * 4);
    float* asB = (float*)w;                      w += align_up((size_t)n * 4 * 4);
    float* adB = (float*)w;                      w += align_up((size_t)n * 4 * 4);
    int* row_ptr = (int*)w;                      w += align_up((size_t)(n + 1) * 4);
    int* counts  = (int*)w;                      w += align_up((size_t)n * 4);
    int* cursor  = (int*)w;                      w += align_up((size_t)n * 4);
    int* src_sorted = (int*)w;                   w += align_up((size_t)et * 4);
    (void)ws_size;

    dim3 blk(256);
    int nodeblocks = (n + 3) / 4;

    // ---- CSR build ----
    zero_int<<<(n + 255) / 256, 256, 0, stream>>>(counts, n);
    hist_kernel<<<(et + 255) / 256, 256, 0, stream>>>(ei, e0, n, counts);
    scan_kernel<<<1, 1024, 0, stream>>>(counts, row_ptr, cursor, n);
    scatter_kernel<<<(et + 255) / 256, 256, 0, stream>>>(ei, e0, n, cursor, src_sorted);

    // ---- fused conversion prologue (x + 4 weights + as/ad zero) ----
    const int nx = n * 256;
    conv_all<<<(nx + 557056 + n * 8 + 255) / 256, blk, 0, stream>>>(
        x, bufA, nx, W1, WT1, W2, WT2, W3, WT3, W4, WT4, asA, n * 8);

    const int mblocks = Mpad / 128;   // 235

    // ---- Layer 1: K=256 -> N=512 (4 heads x 128) ----
    gemm_mfma<<<dim3(4 * mblocks), blk, 0, stream>>>(bufA, WT1, hbuf, n, 256, 512, 4, mblocks,
                                                     a1s, a1d, asA, adA, 4, 128);
    agg_kernel<4, 128, true><<<nodeblocks, blk, 0, stream>>>(hbuf, asA, adA, row_ptr, src_sorted, b1, nullptr, bufB, asB, adB, n);

    // ---- Layer 2: K=512 -> N=512 ----
    gemm_mfma<<<dim3(4 * mblocks), blk, 0, stream>>>(bufB, WT2, hbuf, n, 512, 512, 4, mblocks,
                                                     a2s, a2d, asB, adB, 4, 128);
    agg_kernel<4, 128, true><<<nodeblocks, blk, 0, stream>>>(hbuf, asB, adB, row_ptr, src_sorted, b2, nullptr, bufA, asA, adA, n);

    // ---- Layer 3: K=512 -> N=256 (4 heads x 64) ----
    gemm_mfma<<<dim3(2 * mblocks), blk, 0, stream>>>(bufA, WT3, hbuf, n, 512, 256, 2, mblocks,
                                                     a3s, a3d, asA, adA, 4, 64);
    agg_kernel<4, 64, true><<<nodeblocks, blk, 0, stream>>>(hbuf, asA, adA, row_ptr, src_sorted, b3, nullptr, bufB, asB, adB, n);

    // ---- Layer 4: K=256 -> N=64, 1 head ----
    gemm_mfma<<<dim3(1 * mblocks), blk, 0, stream>>>(bufB, WT4, hbuf, n, 256, 64, 1, mblocks,
                                                     a4s, a4d, asB, adB, 1, 64);
    agg_kernel<1, 64, false><<<nodeblocks, blk, 0, stream>>>(hbuf, asB, adB, row_ptr, src_sorted, b4, (float*)d_out, nullptr, nullptr, nullptr, n);
}

// Round 23
// 560.440 us; speedup vs baseline: 1.3919x; 1.0235x over previous
//
#include <hip/hip_runtime.h>
#include <hip/hip_fp16.h>
#include <math.h>

// ---------------------------------------------------------------------------
// GAT 4-layer forward.  (R22 = exact revert to R16, the measured optimum)
//   Final post-mortem of all measured attacks on the fused agg (77us/layer):
//   - R17-R20 slicing arc: FETCH 238->58MB but time went UP (85-213us);
//     smaller per-edge accesses go instruction/latency-bound.
//   - R21 8-edge unroll: VGPR 36->52, occupancy 62->38%, agg 83.6us;
//     per-wave ILP traded away chip-wide TLP and lowered achieved BW.
//   Structural roofline: agg moves 272MB compulsory traffic (8 XCD x 30MB
//   h-fill, L2 absorbs all within-XCD reuse; FETCH == 8x h exactly) at the
//   measured ~3.6 TB/s random-1KB-gather rate -> 278MB/3.58TBps = 77.6us
//   ~= measured 77.2us (<1%). Every alternative regime measured is slower.
//   GEMM C = A_f16 x B_f16, BKK=64, 32 KB LDS (A|B), 32 MFMAs/barrier,
//   XCD swizzle, fused alpha epilogue, fp16 C. agg: pass-1 softmax stats
//   with LDS e-cache, pass-2 4-edge fp16 gather, fp16 out, zeroes next
//   as/ad ping-pong. Conv prologue fused into ONE dispatch.
// ---------------------------------------------------------------------------

typedef __attribute__((ext_vector_type(8))) _Float16 f16x8;
typedef __attribute__((ext_vector_type(4))) float floatx4;
typedef __attribute__((ext_vector_type(8))) unsigned short usv8;
typedef __attribute__((ext_vector_type(4))) unsigned short usv4;

#define DEG_CAP 256

__device__ __forceinline__ float lrelu(float e) {
    return (e > 0.f) ? e : 0.2f * e;
}
__device__ __forceinline__ void gload16(const void* g, void* l) {
    __builtin_amdgcn_global_load_lds(
        (const __attribute__((address_space(1))) void*)g,
        (__attribute__((address_space(3))) void*)l, 16, 0, 0);
}

// ---------------------------------------------------------------------------
// CSR build
// ---------------------------------------------------------------------------
static __global__ void zero_int(int* __restrict__ p, int n) {
    int i = blockIdx.x * blockDim.x + threadIdx.x;
    if (i < n) p[i] = 0;
}

static __global__ void hist_kernel(const int* __restrict__ ei, int e0, int n_nodes,
                                   int* __restrict__ counts) {
    int e = blockIdx.x * blockDim.x + threadIdx.x;
    int et = e0 + n_nodes;
    if (e >= et) return;
    int d = (e < e0) ? ei[e0 + e] : (e - e0);
    atomicAdd(&counts[d], 1);
}

static __global__ void scan_kernel(const int* __restrict__ counts,
                                   int* __restrict__ row_ptr,
                                   int* __restrict__ cursor, int n) {
    __shared__ int sdata[1024];
    int tid = threadIdx.x;
    int per = (n + 1023) / 1024;
    int start = tid * per;
    int stop = min(start + per, n);
    if (start > n) start = n;
    int s = 0;
    for (int i = start; i < stop; i++) s += counts[i];
    sdata[tid] = s;
    __syncthreads();
    for (int off = 1; off < 1024; off <<= 1) {
        int t = (tid >= off) ? sdata[tid - off] : 0;
        __syncthreads();
        sdata[tid] += t;
        __syncthreads();
    }
    int run = sdata[tid] - s;
    for (int i = start; i < stop; i++) {
        row_ptr[i] = run;
        cursor[i] = run;
        run += counts[i];
    }
    if (stop == n) row_ptr[n] = run;
}

static __global__ void scatter_kernel(const int* __restrict__ ei, int e0, int n_nodes,
                                      int* __restrict__ cursor,
                                      int* __restrict__ src_sorted) {
    int e = blockIdx.x * blockDim.x + threadIdx.x;
    int et = e0 + n_nodes;
    if (e >= et) return;
    int s, d;
    if (e < e0) { s = ei[e]; d = ei[e0 + e]; } else { s = e - e0; d = s; }
    int pos = atomicAdd(&cursor[d], 1);
    src_sorted[pos] = s;
}

// ---------------------------------------------------------------------------
// fused conversion prologue: x -> fp16 A, 4x W -> fp16 W^T, zero as/ad.
// ---------------------------------------------------------------------------
__device__ __forceinline__ void convW_one(const float* W, __half* BT,
                                          int idx, int K, int N) {
    int n = idx / K, k = idx % K;
    float v = (n < N) ? W[(size_t)k * N + n] : 0.f;
    BT[(size_t)n * K + k] = __float2half(v);
}

static __global__ void conv_all(const float* __restrict__ X, __half* __restrict__ A, int nx,
                                const float* __restrict__ W1, __half* __restrict__ BT1,
                                const float* __restrict__ W2, __half* __restrict__ BT2,
                                const float* __restrict__ W3, __half* __restrict__ BT3,
                                const float* __restrict__ W4, __half* __restrict__ BT4,
                                float* __restrict__ zero_as, int nzero) {
    int idx = blockIdx.x * 256 + threadIdx.x;
    if (idx < nx) { A[idx] = __float2half(X[idx]); return; }
    idx -= nx;
    if (idx < 131072) { convW_one(W1, BT1, idx, 256, 512); return; }
    idx -= 131072;
    if (idx < 262144) { convW_one(W2, BT2, idx, 512, 512); return; }
    idx -= 262144;
    if (idx < 131072) { convW_one(W3, BT3, idx, 512, 256); return; }
    idx -= 131072;
    if (idx < 32768)  { convW_one(W4, BT4, idx, 256, 64); return; }
    idx -= 32768;
    if (idx < nzero) zero_as[idx] = 0.f;
}

// ---------------------------------------------------------------------------
// fp16 MFMA GEMM: C = A_f16 x B_f16. BKK=64, 32 KB LDS (A|B), 32 MFMAs per
// barrier, XCD-aware 1-D swizzle, fused alpha epilogue, fp16 C.
// Bank swizzle: 8 chunks/row, XOR with row&7.
// ---------------------------------------------------------------------------
#define BM 128
#define BN 128
#define BKK 64

__launch_bounds__(256, 4)
static __global__ void gemm_mfma(const __half* __restrict__ A,
                                 const __half* __restrict__ B,
                                 __half* __restrict__ C, int M, int K, int N,
                                 int xcols, int mblocks,
                                 const float* __restrict__ asv,
                                 const float* __restrict__ adv,
                                 float* __restrict__ as_out,
                                 float* __restrict__ ad_out,
                                 int Hh, int Cc) {
    __shared__ __align__(16) __half lds[2 * BM * BKK];   // 32 KB
    const int tid  = threadIdx.x;
    const int lane = tid & 63;
    const int wave = tid >> 6;

    const int id = blockIdx.x;
    const int band = id / (8 * xcols);
    const int rem = id - band * 8 * xcols;
    const int band_rows = min(8, mblocks - band * 8);
    const int ry = rem % band_rows;
    const int rx = rem / band_rows;
    const int r0 = (band * 8 + ry) * BM;
    const int c0 = rx * BN;

    const int wm = (wave >> 1) * 64;
    const int wn = (wave & 1) * 64;
    const int q   = lane >> 4;        // 0..3
    const int m16 = lane & 15;

    floatx4 acc[4][4];
#pragma unroll
    for (int i = 0; i < 4; i++)
#pragma unroll
        for (int j = 0; j < 4; j++) acc[i][j] = {0.f, 0.f, 0.f, 0.f};

    char* ldsb = (char*)lds;

#pragma unroll 1
    for (int k0 = 0; k0 < K; k0 += BKK) {
        __syncthreads();
#pragma unroll
        for (int c = 0; c < 4; c++) {
            int slot = c * 256 + tid;      // 0..1023
            int row = slot >> 3;           // 0..127
            int gc  = (slot & 7) ^ (row & 7);
            gload16(A + (size_t)(r0 + row) * K + k0 + gc * 8,
                    ldsb + slot * 16);                       // A
            gload16(B + (size_t)(c0 + row) * K + k0 + gc * 8,
                    ldsb + 16384 + slot * 16);               // B
        }
        __syncthreads();
#pragma unroll
        for (int ks = 0; ks < 2; ks++) {
            f16x8 af[4], bf[4];
#pragma unroll
            for (int i = 0; i < 4; i++) {
                int row = wm + i * 16 + m16;
                int ch  = (q + ks * 4) ^ (row & 7);
                af[i] = *(const f16x8*)(ldsb + (row * 8 + ch) * 16);
            }
#pragma unroll
            for (int j = 0; j < 4; j++) {
                int row = wn + j * 16 + m16;
                int ch  = (q + ks * 4) ^ (row & 7);
                bf[j] = *(const f16x8*)(ldsb + 16384 + (row * 8 + ch) * 16);
            }
#pragma unroll
            for (int i = 0; i < 4; i++)
#pragma unroll
                for (int j = 0; j < 4; j++)
                    acc[i][j] = __builtin_amdgcn_mfma_f32_16x16x32_f16(
                        af[i], bf[j], acc[i][j], 0, 0, 0);
        }
    }
    // C store (fp16). C/D layout: col = lane&15, row = (lane>>4)*4 + reg
#pragma unroll
    for (int i = 0; i < 4; i++)
#pragma unroll
        for (int j = 0; j < 4; j++)
#pragma unroll
            for (int r = 0; r < 4; r++) {
                int row = r0 + wm + i * 16 + q * 4 + r;
                int col = c0 + wn + j * 16 + m16;
                if (row < M && col < N)
                    C[(size_t)row * N + col] = __float2half(acc[i][j][r]);
            }
    // fused alpha epilogue: wave's 64-col chunk is head-uniform (C in {64,128}).
    if (c0 + wn < N) {
        int head = (c0 + wn) / Cc;
#pragma unroll
        for (int i = 0; i < 4; i++)
#pragma unroll
            for (int r = 0; r < 4; r++) {
                float ps = 0.f, pd = 0.f;
#pragma unroll
                for (int j = 0; j < 4; j++) {
                    int c = c0 + wn + j * 16 + m16;
                    float v = acc[i][j][r];
                    ps = fmaf(v, asv[c], ps);
                    pd = fmaf(v, adv[c], pd);
                }
#pragma unroll
                for (int off = 1; off < 16; off <<= 1) {
                    ps += __shfl_xor(ps, off);
                    pd += __shfl_xor(pd, off);
                }
                if (m16 == 0) {
                    int row = r0 + wm + i * 16 + q * 4 + r;
                    if (row < M) {
                        atomicAdd(&as_out[(size_t)row * Hh + head], ps);
                        atomicAdd(&ad_out[(size_t)row * Hh + head], pd);
                    }
                }
            }
    }
}

// ---------------------------------------------------------------------------
// gather helper: acc[r] += w * h_fp16[off+r]
// ---------------------------------------------------------------------------
template <int R>
__device__ __forceinline__ void accum_row(const __half* hptr, size_t off, float w,
                                          float* acc) {
    const __half* p = hptr + off;
    if constexpr (R == 8) {
        float4 raw = *(const float4*)p;          // 8 halves, one dwordx4
        const __half* hv = (const __half*)&raw;
#pragma unroll
        for (int r = 0; r < 8; r++) acc[r] = fmaf(__half2float(hv[r]), w, acc[r]);
    } else if constexpr (R == 4) {
        float2 raw = *(const float2*)p;
        const __half* hv = (const __half*)&raw;
#pragma unroll
        for (int r = 0; r < 4; r++) acc[r] = fmaf(__half2float(hv[r]), w, acc[r]);
    } else {
        acc[0] = fmaf(__half2float(*p), w, acc[0]);
    }
}

// ---------------------------------------------------------------------------
// aggregation: one wave/node. Pass 1 caches e in LDS (DEG_CAP), reduces m,l.
// Pass 2: 4-edge unroll, w from cached e, fp16 gather. Output fp16 (next A)
// or fp32 (final). Epilogue zeroes next layer's as/ad ping-pong.
// ---------------------------------------------------------------------------
template <int H, int C, bool F16OUT>
__launch_bounds__(256)
static __global__ void agg_kernel(const __half* __restrict__ h,
                                  const float* __restrict__ as_arr,
                                  const float* __restrict__ ad_arr,
                                  const int* __restrict__ row_ptr,
                                  const int* __restrict__ src_sorted,
                                  const float* __restrict__ bias,
                                  float* __restrict__ outf,
                                  __half* __restrict__ outh,
                                  float* __restrict__ znext_as,
                                  float* __restrict__ znext_ad, int n_nodes) {
    constexpr int R = H * C / 64;
    constexpr int G = 64 / H;
    constexpr int K = H * C;
    __shared__ float lds_e[4][DEG_CAP * H];
    int wave = threadIdx.x >> 6;
    int lane = threadIdx.x & 63;
    int n = blockIdx.x * 4 + wave;
    if (n >= n_nodes) return;
    int beg = row_ptr[n], end = row_ptr[n + 1];
    float* we = lds_e[wave];

    // ---- pass 1: per-head m, l; cache e in LDS ----
    float ad_h[H], m_h[H], l_h[H];
#pragma unroll
    for (int hh = 0; hh < H; hh++) {
        ad_h[hh] = ad_arr[(size_t)n * H + hh];
        m_h[hh] = -INFINITY;
        l_h[hh] = 0.f;
    }
    for (int base = beg; base < end; base += 64) {
        int j = base + lane;
        bool ok = j < end;
        float e_h[H];
        if (ok) {
            int s = src_sorted[j];
            if constexpr (H == 4) {
                float4 a = ((const float4*)as_arr)[s];
                e_h[0] = lrelu(a.x + ad_h[0]);
                e_h[1] = lrelu(a.y + ad_h[1]);
                e_h[2] = lrelu(a.z + ad_h[2]);
                e_h[3] = lrelu(a.w + ad_h[3]);
            } else {
                e_h[0] = lrelu(as_arr[s] + ad_h[0]);
            }
            int idx = j - beg;
            if (idx < DEG_CAP) {
                if constexpr (H == 4) {
                    *(float4*)&we[idx * 4] = make_float4(e_h[0], e_h[1], e_h[2], e_h[3]);
                } else {
                    we[idx] = e_h[0];
                }
            }
        } else {
#pragma unroll
            for (int hh = 0; hh < H; hh++) e_h[hh] = -INFINITY;
        }
#pragma unroll
        for (int hh = 0; hh < H; hh++) {
            float cm = e_h[hh];
#pragma unroll
            for (int off = 1; off < 64; off <<= 1) cm = fmaxf(cm, __shfl_xor(cm, off));
            float newm = fmaxf(m_h[hh], cm);
            float p = ok ? __expf(e_h[hh] - newm) : 0.f;
#pragma unroll
            for (int off = 1; off < 64; off <<= 1) p += __shfl_xor(p, off);
            l_h[hh] = l_h[hh] * __expf(m_h[hh] - newm) + p;
            m_h[hh] = newm;
        }
    }
    int myh = lane / G;
    float mm, adm, inv;
    if constexpr (H == 4) {
        mm  = m_h[0];  mm  = (myh == 1) ? m_h[1] : mm;  mm  = (myh == 2) ? m_h[2] : mm;  mm  = (myh == 3) ? m_h[3] : mm;
        float ll = l_h[0]; ll = (myh == 1) ? l_h[1] : ll; ll = (myh == 2) ? l_h[2] : ll; ll = (myh == 3) ? l_h[3] : ll;
        adm = ad_h[0]; adm = (myh == 1) ? ad_h[1] : adm; adm = (myh == 2) ? ad_h[2] : adm; adm = (myh == 3) ? ad_h[3] : adm;
        inv = 1.f / ll;
    } else {
        mm = m_h[0]; adm = ad_h[0]; inv = 1.f / l_h[0];
    }

    // ---- pass 2: gather, w from cached e (4-edge unroll) ----
    float acc[R];
#pragma unroll
    for (int r = 0; r < R; r++) acc[r] = 0.f;

    int j = beg;
    for (; j + 3 < end; j += 4) {
        int i0 = j - beg;
        int s0 = src_sorted[j];
        int s1 = src_sorted[j + 1];
        int s2 = src_sorted[j + 2];
        int s3 = src_sorted[j + 3];
        float e0, e1, e2, e3;
        if (i0 + 3 < DEG_CAP) {
            e0 = we[(i0 + 0) * H + myh];
            e1 = we[(i0 + 1) * H + myh];
            e2 = we[(i0 + 2) * H + myh];
            e3 = we[(i0 + 3) * H + myh];
        } else {
            e0 = lrelu(as_arr[(size_t)s0 * H + myh] + adm);
            e1 = lrelu(as_arr[(size_t)s1 * H + myh] + adm);
            e2 = lrelu(as_arr[(size_t)s2 * H + myh] + adm);
            e3 = lrelu(as_arr[(size_t)s3 * H + myh] + adm);
        }
        float w0 = __expf(e0 - mm) * inv;
        float w1 = __expf(e1 - mm) * inv;
        float w2 = __expf(e2 - mm) * inv;
        float w3 = __expf(e3 - mm) * inv;
        accum_row<R>(h, (size_t)s0 * K + lane * R, w0, acc);
        accum_row<R>(h, (size_t)s1 * K + lane * R, w1, acc);
        accum_row<R>(h, (size_t)s2 * K + lane * R, w2, acc);
        accum_row<R>(h, (size_t)s3 * K + lane * R, w3, acc);
    }
    for (; j < end; j++) {
        int i0 = j - beg;
        int s0 = src_sorted[j];
        float e0 = (i0 < DEG_CAP) ? we[i0 * H + myh]
                                  : lrelu(as_arr[(size_t)s0 * H + myh] + adm);
        float w0 = __expf(e0 - mm) * inv;
        accum_row<R>(h, (size_t)s0 * K + lane * R, w0, acc);
    }

    // ---- epilogue: bias + relu; zero next layer's as/ad ----
    if (znext_as != nullptr && lane == 0) {
        if constexpr (H == 4) {
            *(float4*)&znext_as[(size_t)n * 4] = make_float4(0.f, 0.f, 0.f, 0.f);
            *(float4*)&znext_ad[(size_t)n * 4] = make_float4(0.f, 0.f, 0.f, 0.f);
        } else {
            znext_as[n] = 0.f;
            znext_ad[n] = 0.f;
        }
    }
    float vout[R];
#pragma unroll
    for (int r = 0; r < R; r++)
        vout[r] = fmaxf(acc[r] + bias[lane * R + r], 0.f);

    if constexpr (F16OUT) {
        unsigned short hv[R];
#pragma unroll
        for (int r = 0; r < R; r++)
            hv[r] = __half_as_ushort(__float2half(vout[r]));
        size_t base = (size_t)n * K + lane * R;
        if constexpr (R == 8) {
            usv8 v = {hv[0], hv[1], hv[2], hv[3], hv[4], hv[5], hv[6], hv[7]};
            *(usv8*)((unsigned short*)outh + base) = v;
        } else if constexpr (R == 4) {
            usv4 v = {hv[0], hv[1], hv[2], hv[3]};
            *(usv4*)((unsigned short*)outh + base) = v;
        } else {
#pragma unroll
            for (int r = 0; r < R; r++) ((unsigned short*)outh)[base + r] = hv[r];
        }
    } else {
#pragma unroll
        for (int r = 0; r < R; r++)
            outf[(size_t)n * K + lane * R + r] = vout[r];
    }
}

// ---------------------------------------------------------------------------

static inline size_t align_up(size_t x) { return (x + 255) & ~(size_t)255; }

extern "C" void kernel_launch(void* const* d_in, const int* in_sizes, int n_in,
                              void* d_out, int out_size, void* d_ws, size_t ws_size,
                              hipStream_t stream) {
    const float* x   = (const float*)d_in[0];
    const int*   ei  = (const int*)d_in[1];
    const float* W1  = (const float*)d_in[2];
    const float* a1s = (const float*)d_in[3];
    const float* a1d = (const float*)d_in[4];
    const float* b1  = (const float*)d_in[5];
    const float* W2  = (const float*)d_in[6];
    const float* a2s = (const float*)d_in[7];
    const float* a2d = (const float*)d_in[8];
    const float* b2  = (const float*)d_in[9];
    const float* W3  = (const float*)d_in[10];
    const float* a3s = (const float*)d_in[11];
    const float* a3d = (const float*)d_in[12];
    const float* b3  = (const float*)d_in[13];
    const float* W4  = (const float*)d_in[14];
    const float* a4s = (const float*)d_in[15];
    const float* a4d = (const float*)d_in[16];
    const float* b4  = (const float*)d_in[17];

    const int n  = in_sizes[0] / 256;    // 30000
    const int e0 = in_sizes[1] / 2;      // 480000
    const int et = e0 + n;
    const int Mpad = ((n + 127) / 128) * 128;   // 30080

    // workspace layout (~100 MB)
    char* w = (char*)d_ws;
    __half* bufA = (__half*)w;                   w += align_up((size_t)Mpad * 512 * 2);
    __half* bufB = (__half*)w;                   w += align_up((size_t)Mpad * 512 * 2);
    __half* hbuf = (__half*)w;                   w += align_up((size_t)Mpad * 512 * 2);
    __half* WT1 = (__half*)w;                    w += align_up((size_t)512 * 256 * 2);
    __half* WT2 = (__half*)w;                    w += align_up((size_t)512 * 512 * 2);
    __half* WT3 = (__half*)w;                    w += align_up((size_t)256 * 512 * 2);
    __half* WT4 = (__half*)w;                    w += align_up((size_t)128 * 256 * 2);
    float* asA = (float*)w;                      w += align_up((size_t)n * 4 * 4);
    float* adA = (float*)w;                      w += align_up((size_t)n * 4 * 4);
    float* asB = (float*)w;                      w += align_up((size_t)n * 4 * 4);
    float* adB = (float*)w;                      w += align_up((size_t)n * 4 * 4);
    int* row_ptr = (int*)w;                      w += align_up((size_t)(n + 1) * 4);
    int* counts  = (int*)w;                      w += align_up((size_t)n * 4);
    int* cursor  = (int*)w;                      w += align_up((size_t)n * 4);
    int* src_sorted = (int*)w;                   w += align_up((size_t)et * 4);
    (void)ws_size;

    dim3 blk(256);
    int nodeblocks = (n + 3) / 4;

    // ---- CSR build ----
    zero_int<<<(n + 255) / 256, 256, 0, stream>>>(counts, n);
    hist_kernel<<<(et + 255) / 256, 256, 0, stream>>>(ei, e0, n, counts);
    scan_kernel<<<1, 1024, 0, stream>>>(counts, row_ptr, cursor, n);
    scatter_kernel<<<(et + 255) / 256, 256, 0, stream>>>(ei, e0, n, cursor, src_sorted);

    // ---- fused conversion prologue (x + 4 weights + as/ad zero) ----
    const int nx = n * 256;
    conv_all<<<(nx + 557056 + n * 8 + 255) / 256, blk, 0, stream>>>(
        x, bufA, nx, W1, WT1, W2, WT2, W3, WT3, W4, WT4, asA, n * 8);

    const int mblocks = Mpad / 128;   // 235

    // ---- Layer 1: K=256 -> N=512 (4 heads x 128) ----
    gemm_mfma<<<dim3(4 * mblocks), blk, 0, stream>>>(bufA, WT1, hbuf, n, 256, 512, 4, mblocks,
                                                     a1s, a1d, asA, adA, 4, 128);
    agg_kernel<4, 128, true><<<nodeblocks, blk, 0, stream>>>(hbuf, asA, adA, row_ptr, src_sorted, b1, nullptr, bufB, asB, adB, n);

    // ---- Layer 2: K=512 -> N=512 ----
    gemm_mfma<<<dim3(4 * mblocks), blk, 0, stream>>>(bufB, WT2, hbuf, n, 512, 512, 4, mblocks,
                                                     a2s, a2d, asB, adB, 4, 128);
    agg_kernel<4, 128, true><<<nodeblocks, blk, 0, stream>>>(hbuf, asB, adB, row_ptr, src_sorted, b2, nullptr, bufA, asA, adA, n);

    // ---- Layer 3: K=512 -> N=256 (4 heads x 64) ----
    gemm_mfma<<<dim3(2 * mblocks), blk, 0, stream>>>(bufA, WT3, hbuf, n, 512, 256, 2, mblocks,
                                                     a3s, a3d, asA, adA, 4, 64);
    agg_kernel<4, 64, true><<<nodeblocks, blk, 0, stream>>>(hbuf, asA, adA, row_ptr, src_sorted, b3, nullptr, bufB, asB, adB, n);

    // ---- Layer 4: K=256 -> N=64, 1 head ----
    gemm_mfma<<<dim3(1 * mblocks), blk, 0, stream>>>(bufB, WT4, hbuf, n, 256, 64, 1, mblocks,
                                                     a4s, a4d, asB, adB, 1, 64);
    agg_kernel<1, 64, false><<<nodeblocks, blk, 0, stream>>>(hbuf, asB, adB, row_ptr, src_sorted, b4, (float*)d_out, nullptr, nullptr, nullptr, n);
}